// Round 1
// baseline (2652.348 us; speedup 1.0000x reference)
//
#include <hip/hip_runtime.h>
#include <cstdint>
#include <cstddef>

#define BATCH 128
#define TLEN 4096
#define KS 64
#define CHUNK 64
#define NCHUNK 64  // chunks over t=1..4095; chunk c: t in [64c+1, min(64c+64, 4095)]

// ---------------------------------------------------------------------------
// Forward Viterbi: one wave per batch. Lane j owns destination state j.
// Bit-exact vs reference: score = s[i] + T[i][j] (fp32), strict-greater
// ascending argmax (= jnp.argmax first-occurrence), state = max + emit.
// Backpointers stored as bytes in ws.
// ---------------------------------------------------------------------------
__global__ __launch_bounds__(64, 1) void crf_fwd(
    const float* __restrict__ pot, const float* __restrict__ trans,
    unsigned char* __restrict__ bp, int* __restrict__ last_tag) {
  const int b = blockIdx.x;
  const int j = threadIdx.x;
  __shared__ float s[2][KS];

  // Transitions column j -> registers (64 VGPRs), coalesced across lanes per i.
  float c[KS];
#pragma unroll
  for (int i = 0; i < KS; ++i) c[i] = trans[i * KS + j];

  const float* pb = pot + (size_t)b * TLEN * KS;
  unsigned char* bpb = bp + (size_t)b * TLEN * KS;

  s[0][j] = pb[j];  // t = 0 init
  __syncthreads();

  int cur = 0;
  float emit = pb[KS + j];  // prefetch t=1 emission
  for (int t = 1; t < TLEN; ++t) {
    // prefetch next emission (hides global latency behind this step's compute)
    float emit_next = (t + 1 < TLEN) ? pb[(t + 1) * KS + j] : 0.0f;

    // broadcast-read state into registers via b128 loads
    float sv[KS];
    const float4* sc4 = (const float4*)s[cur];
#pragma unroll
    for (int q = 0; q < KS / 4; ++q) {
      float4 v = sc4[q];
      sv[4 * q + 0] = v.x;
      sv[4 * q + 1] = v.y;
      sv[4 * q + 2] = v.z;
      sv[4 * q + 3] = v.w;
    }

    float best = sv[0] + c[0];
    int bi = 0;
#pragma unroll
    for (int i = 1; i < KS; ++i) {
      float sc = sv[i] + c[i];
      if (sc > best) bi = i;          // first-occurrence tie-break (strict >)
      best = fmaxf(best, sc);
    }

    bpb[t * KS + j] = (unsigned char)bi;
    s[cur ^ 1][j] = best + emit;
    emit = emit_next;
    cur ^= 1;
    __syncthreads();
  }

  // final argmax (first occurrence)
  if (j == 0) {
    const float* fs = s[cur];
    float bbest = fs[0];
    int bt = 0;
    for (int i = 1; i < KS; ++i) {
      if (fs[i] > bbest) { bbest = fs[i]; bt = i; }
    }
    last_tag[b] = bt;
  }
}

// ---------------------------------------------------------------------------
// Backtrack phase 1: per (batch, chunk), all 64 lanes speculatively chase
// every possible entering tag through the chunk -> map[b][c][j].
// ---------------------------------------------------------------------------
__global__ __launch_bounds__(64) void crf_maps(
    const unsigned char* __restrict__ bp, unsigned char* __restrict__ map) {
  const int b = blockIdx.x;
  const int c = blockIdx.y;
  const int j = threadIdx.x;
  const int lo = CHUNK * c + 1;
  const int hi = min(CHUNK * c + CHUNK, TLEN - 1);
  const unsigned char* bpb = bp + (size_t)b * TLEN * KS;
  int tag = j;
  for (int t = hi; t >= lo; --t) tag = bpb[t * KS + tag];
  map[((size_t)b * NCHUNK + c) * KS + j] = (unsigned char)tag;
}

// ---------------------------------------------------------------------------
// Backtrack phase 2: compose maps per batch (serial over 64 chunks, parallel
// over batches). e[b][c] = tag at t = hi_c. Also writes tags[b][T-1].
// ---------------------------------------------------------------------------
__global__ void crf_compose(const unsigned char* __restrict__ map,
                            const int* __restrict__ last_tag,
                            unsigned char* __restrict__ e,
                            int* __restrict__ tags_out) {
  const int b = blockIdx.x * blockDim.x + threadIdx.x;
  if (b >= BATCH) return;
  int cur = last_tag[b];
  tags_out[(size_t)b * TLEN + (TLEN - 1)] = cur;
  for (int c = NCHUNK - 1; c >= 0; --c) {
    e[(size_t)b * NCHUNK + c] = (unsigned char)cur;
    cur = map[((size_t)b * NCHUNK + c) * KS + cur];
  }
}

// ---------------------------------------------------------------------------
// Backtrack phase 3: per (batch, chunk), re-chase from known entering tag,
// recording the path. Parallel over B*NCHUNK = 8192 threads.
// ---------------------------------------------------------------------------
__global__ void crf_extract(const unsigned char* __restrict__ bp,
                            const unsigned char* __restrict__ e,
                            int* __restrict__ tags_out) {
  const int idx = blockIdx.x * blockDim.x + threadIdx.x;  // b*NCHUNK + c
  if (idx >= BATCH * NCHUNK) return;
  const int b = idx >> 6;
  const int c = idx & (NCHUNK - 1);
  const int lo = CHUNK * c + 1;
  const int hi = min(CHUNK * c + CHUNK, TLEN - 1);
  const unsigned char* bpb = bp + (size_t)b * TLEN * KS;
  int* to = tags_out + (size_t)b * TLEN;
  int tag = e[(size_t)b * NCHUNK + c];
  for (int t = hi; t >= lo; --t) {
    tag = bpb[t * KS + tag];
    to[t - 1] = tag;
  }
}

// ---------------------------------------------------------------------------
// Sequence lengths = sum(mask) per batch.
// ---------------------------------------------------------------------------
__global__ __launch_bounds__(64) void crf_lens(const int* __restrict__ mask,
                                               int* __restrict__ out) {
  const int b = blockIdx.x;
  const int l = threadIdx.x;
  const int* mb = mask + (size_t)b * TLEN;
  int sum = 0;
  for (int t = l; t < TLEN; t += 64) sum += mb[t];
#pragma unroll
  for (int off = 32; off > 0; off >>= 1) sum += __shfl_down(sum, off, 64);
  if (l == 0) out[b] = sum;
}

extern "C" void kernel_launch(void* const* d_in, const int* in_sizes, int n_in,
                              void* d_out, int out_size, void* d_ws,
                              size_t ws_size, hipStream_t stream) {
  const float* pot = (const float*)d_in[0];        // (128, 4096, 64) fp32
  const float* trans = (const float*)d_in[1];      // (64, 64) fp32
  const int* mask = (const int*)d_in[2];           // (128, 4096) int32

  int* out = (int*)d_out;                          // [tags: 128*4096][lens: 128]
  int* tags_out = out;
  int* lens_out = out + (size_t)BATCH * TLEN;

  // workspace layout
  char* w = (char*)d_ws;
  unsigned char* bp = (unsigned char*)w;                       // 33,554,432 B
  unsigned char* map = bp + (size_t)BATCH * TLEN * KS;         //    524,288 B
  unsigned char* e = map + (size_t)BATCH * NCHUNK * KS;        //      8,192 B
  int* last_tag = (int*)(e + (size_t)BATCH * NCHUNK);          //        512 B

  crf_fwd<<<BATCH, 64, 0, stream>>>(pot, trans, bp, last_tag);
  crf_lens<<<BATCH, 64, 0, stream>>>(mask, lens_out);
  crf_maps<<<dim3(BATCH, NCHUNK), 64, 0, stream>>>(bp, map);
  crf_compose<<<1, BATCH, 0, stream>>>(map, last_tag, e, tags_out);
  crf_extract<<<(BATCH * NCHUNK + 255) / 256, 256, 0, stream>>>(bp, e, tags_out);
}